// Round 6
// baseline (178.267 us; speedup 1.0000x reference)
//
#include <hip/hip_runtime.h>

static constexpr int C    = 64;
static constexpr int H    = 128;
static constexpr int W    = 128;
static constexpr int NPIX = H * W;      // 16384
static constexpr int PAD  = 3;          // WS=7 -> +-3

// ---------------------------------------------------------------------------
// 1) conv1x1. Each wave: 64 pixels x 16 output channels; W/b wave-uniform ->
//    scalar loads feeding v_fmac v,s,v; 16 independent acc chains.
//    grid (NPIX/64, 3) = 768 blocks, block 256
// ---------------------------------------------------------------------------
__global__ __launch_bounds__(256) void k_conv(
    const float* __restrict__ x,
    const float* __restrict__ Wq, const float* __restrict__ bq,
    const float* __restrict__ Wk, const float* __restrict__ bk,
    const float* __restrict__ Wv, const float* __restrict__ bv,
    float* __restrict__ qT, float* __restrict__ ko, float* __restrict__ vo)
{
    const int tid  = threadIdx.x;
    const int lane = tid & 63;
    const int p    = blockIdx.x * 64 + lane;
    const int o0   = __builtin_amdgcn_readfirstlane((tid >> 6) * 16);
    const int z    = blockIdx.y;
    const float* Wm = (z == 0) ? Wq : (z == 1) ? Wk : Wv;
    const float* bm = (z == 0) ? bq : (z == 1) ? bk : bv;

    float xr[C];
#pragma unroll
    for (int c = 0; c < C; ++c) xr[c] = x[c * NPIX + p];

    float acc[16];
#pragma unroll
    for (int j = 0; j < 16; ++j) acc[j] = bm[o0 + j];

#pragma unroll 8
    for (int c = 0; c < C; ++c) {
        const float xv = xr[c];
#pragma unroll
        for (int j = 0; j < 16; ++j)
            acc[j] += Wm[(o0 + j) * C + c] * xv;
    }

    if (z == 0) {
#pragma unroll
        for (int j = 0; j < 16; j += 4)
            *(float4*)(qT + (size_t)p * C + o0 + j) =
                make_float4(acc[j], acc[j + 1], acc[j + 2], acc[j + 3]);
    } else {
        float* outm = (z == 1) ? ko : vo;
#pragma unroll
        for (int j = 0; j < 16; ++j)
            outm[(o0 + j) * NPIX + p] = acc[j];
    }
}

// ---------------------------------------------------------------------------
// 2) row Gram: S[h, w, kk] = sum_c q[c,h,w] * k[c,h,kk]
//    k column in VGPRs (coalesced loads); q row wave-uniform -> s_load.
//    grid (H, 8) = 1024 blocks, block 256
// ---------------------------------------------------------------------------
__global__ __launch_bounds__(256) void k_gram(
    const float* __restrict__ qT, const float* __restrict__ kmat,
    float* __restrict__ S)
{
    const int h   = blockIdx.x;
    const int w0  = blockIdx.y * 16;
    const int tid = threadIdx.x;
    const int kk  = tid & 127;
    const int wh  = tid >> 7;               // 0/1, uniform per wave

    float ksr[C];
#pragma unroll
    for (int c = 0; c < C; ++c) ksr[c] = kmat[c * NPIX + h * W + kk];

    for (int j = 0; j < 8; ++j) {
        int wu = __builtin_amdgcn_readfirstlane(w0 + wh * 8 + j);
        const float* qrow = qT + (size_t)(h * W + wu) * C;  // SGPR base
        float a0 = 0.f, a1 = 0.f, a2 = 0.f, a3 = 0.f;
#pragma unroll
        for (int c = 0; c < C; c += 4) {
            a0 += qrow[c + 0] * ksr[c + 0];
            a1 += qrow[c + 1] * ksr[c + 1];
            a2 += qrow[c + 2] * ksr[c + 2];
            a3 += qrow[c + 3] * ksr[c + 3];
        }
        S[(h * W + wu) * W + kk] = (a0 + a1) + (a2 + a3);
    }
}

// ---------------------------------------------------------------------------
// 3) fused 7x7 box sum of v. grid (C, H/16), block 256
// ---------------------------------------------------------------------------
__global__ __launch_bounds__(256) void k_box(
    const float* __restrict__ v, float* __restrict__ Vs)
{
    __shared__ float vt[22][128];    // rows h0-3 .. h0+18, zero-padded
    __shared__ float vh[22][128];    // horizontal 7-sums
    const int c   = blockIdx.x;
    const int h0  = blockIdx.y * 16;
    const int tid = threadIdx.x;

    for (int i = tid; i < 22 * 128; i += 256) {
        int r = i >> 7, w = i & 127;
        int h = h0 - 3 + r;
        vt[r][w] = (h >= 0 && h < H) ? v[c * NPIX + h * W + w] : 0.f;
    }
    __syncthreads();
    for (int i = tid; i < 22 * 128; i += 256) {
        int r = i >> 7, w = i & 127;
        float s = 0.f;
#pragma unroll
        for (int d = -PAD; d <= PAD; ++d) {
            int wj = w + d;
            if (wj >= 0 && wj < W) s += vt[r][wj];
        }
        vh[r][w] = s;
    }
    __syncthreads();
    for (int i = tid; i < 16 * 128; i += 256) {
        int r = i >> 7, w = i & 127;
        float s = 0.f;
#pragma unroll
        for (int d = 0; d < 7; ++d) s += vh[r + d][w];
        Vs[c * NPIX + (h0 + r) * W + w] = s;
    }
}

// ---------------------------------------------------------------------------
// 4) fused vertical-sum + diagonal-sum + softmax:
//    logits[h,w,kk] = sum_dd D[w+dd, kk+dd],  D[w',kk'] = sum_{h'} S[h',w',kk']
//    (vertical and diagonal sums commute). Per block: h fixed, 32-w tile.
//    Vertical sum in registers (19 staging accs), one LDS dump (38x132, 2-way
//    conflicts = free), diagonal 7-tap from LDS, group-of-8 shuffle softmax.
//    grid (H, 4) = 512 blocks, block 256
// ---------------------------------------------------------------------------
__global__ __launch_bounds__(256) void k_attn(
    const float* __restrict__ S, float* __restrict__ attn)
{
    __shared__ float D[38][132];     // ~20 KB
    const int h   = blockIdx.x;
    const int w0  = blockIdx.y * 32;
    const int tid = threadIdx.x;

    float st[19];                    // 38*128 / 256 = 19 elements per thread
#pragma unroll
    for (int s = 0; s < 19; ++s) st[s] = 0.f;

    for (int dh = -PAD; dh <= PAD; ++dh) {
        int hj = h + dh;
        if (hj < 0 || hj >= H) continue;
        const float* Srow = S + (size_t)hj * W * W;
#pragma unroll
        for (int s = 0; s < 19; ++s) {
            int i   = s * 256 + tid;
            int row = i >> 7;                 // 0..37
            int col = i & 127;
            int wp  = w0 - 3 + row;
            if (wp >= 0 && wp < W)
                st[s] += Srow[wp * W + col];
        }
    }
#pragma unroll
    for (int s = 0; s < 19; ++s) {
        int i = s * 256 + tid;
        D[i >> 7][i & 127] = st[s];
    }
    __syncthreads();

    const int wl = tid >> 3;          // 0..31 (w within tile)
    const int g  = tid & 7;           // kk % 8
    float lg[16];
#pragma unroll
    for (int r = 0; r < 16; ++r) {
        int kk = g + 8 * r;
        float a = 0.f;
#pragma unroll
        for (int dd = -PAD; dd <= PAD; ++dd) {
            int kj = kk + dd;
            if (kj >= 0 && kj < W)
                a += D[wl + 3 + dd][kj];
        }
        lg[r] = a;
    }

    float m = lg[0];
#pragma unroll
    for (int r = 1; r < 16; ++r) m = fmaxf(m, lg[r]);
#pragma unroll
    for (int off = 1; off <= 4; off <<= 1) m = fmaxf(m, __shfl_xor(m, off));
    float ssum = 0.f;
#pragma unroll
    for (int r = 0; r < 16; ++r) { lg[r] = __expf(lg[r] - m); ssum += lg[r]; }
#pragma unroll
    for (int off = 1; off <= 4; off <<= 1) ssum += __shfl_xor(ssum, off);
    float inv = 1.f / ssum;

    float* arow = attn + (size_t)h * NPIX + (size_t)(w0 + wl) * W;
#pragma unroll
    for (int r = 0; r < 16; ++r) arow[g + 8 * r] = lg[r] * inv;
}

// ---------------------------------------------------------------------------
// 5) out[c,h,w] = sum_kk attn[h,w,kk] * Vs[c,h,kk]  — lanes = w, channels
//    wave-uniform -> Vs via s_load; attn LDS-staged (padded). 8 acc chains.
//    grid (H, 4) = 512 blocks, block 256
// ---------------------------------------------------------------------------
__global__ __launch_bounds__(256) void k_out(
    const float* __restrict__ attn, const float* __restrict__ Vs,
    float* __restrict__ out)
{
    __shared__ float As[W][65];      // [w][kk-chunk of 64], 33.3 KB
    const int h   = blockIdx.x;
    const int tid = threadIdx.x;
    const int w   = tid & 127;
    const int c0  = __builtin_amdgcn_readfirstlane(
                        blockIdx.y * 16 + (tid >> 7) * 8);
    const int hb  = h * W;

    float acc[8];
#pragma unroll
    for (int j = 0; j < 8; ++j) acc[j] = 0.f;

    for (int kc = 0; kc < W; kc += 64) {
        __syncthreads();
        for (int i = tid; i < W * 64; i += 256) {
            int kk = i & 63, ww = i >> 6;
            As[ww][kk] = attn[(size_t)h * NPIX + ww * W + kc + kk];
        }
        __syncthreads();
#pragma unroll 4
        for (int kk = 0; kk < 64; ++kk) {
            float a = As[w][kk];
#pragma unroll
            for (int j = 0; j < 8; ++j)
                acc[j] += Vs[(size_t)(c0 + j) * NPIX + hb + kc + kk] * a;
        }
    }

#pragma unroll
    for (int j = 0; j < 8; ++j)
        out[(size_t)(c0 + j) * NPIX + hb + w] = acc[j];
}

// ---------------------------------------------------------------------------
// Workspace: 8M floats = 32 MB used (ws is 268 MB), non-overlapping:
//   qT [0,1M)  k [1M,2M)  v [2M,3M)  S [3M,5M)  Vs [5M,6M)  attn [6M,8M)
// ---------------------------------------------------------------------------
extern "C" void kernel_launch(void* const* d_in, const int* in_sizes, int n_in,
                              void* d_out, int out_size, void* d_ws, size_t ws_size,
                              hipStream_t stream)
{
    const float* x  = (const float*)d_in[0];
    const float* Wq = (const float*)d_in[1];
    const float* bq = (const float*)d_in[2];
    const float* Wk = (const float*)d_in[3];
    const float* bk = (const float*)d_in[4];
    const float* Wv = (const float*)d_in[5];
    const float* bv = (const float*)d_in[6];
    float* out = (float*)d_out;

    float* ws = (float*)d_ws;
    const size_t NQ = (size_t)C * NPIX;       // 1M floats
    const size_t NS = (size_t)H * W * W;      // 2M floats

    float* qT   = ws;
    float* k    = ws + NQ;
    float* v    = ws + 2 * NQ;
    float* S    = ws + 3 * NQ;
    float* Vsum = ws + 3 * NQ + NS;
    float* attn = ws + 4 * NQ + NS;

    k_conv<<<dim3(NPIX / 64, 3), 256, 0, stream>>>(x, Wq, bq, Wk, bk, Wv, bv, qT, k, v);
    k_gram<<<dim3(H, 8), 256, 0, stream>>>(qT, k, S);
    k_box<<<dim3(C, H / 16), 256, 0, stream>>>(v, Vsum);
    k_attn<<<dim3(H, 4), 256, 0, stream>>>(S, attn);
    k_out<<<dim3(H, 4), 256, 0, stream>>>(attn, Vsum, out);
}

// Round 7
// 154.350 us; speedup vs baseline: 1.1550x; 1.1550x over previous
//
#include <hip/hip_runtime.h>

static constexpr int C    = 64;
static constexpr int H    = 128;
static constexpr int W    = 128;
static constexpr int NPIX = H * W;      // 16384
static constexpr int PAD  = 3;          // WS=7 -> +-3

// ---------------------------------------------------------------------------
// 1) conv1x1. Each wave: 64 pixels x 16 output channels; W/b wave-uniform ->
//    scalar loads feeding v_fmac v,s,v; 16 independent acc chains.
//    grid (NPIX/64, 3) = 768 blocks, block 256
// ---------------------------------------------------------------------------
__global__ __launch_bounds__(256) void k_conv(
    const float* __restrict__ x,
    const float* __restrict__ Wq, const float* __restrict__ bq,
    const float* __restrict__ Wk, const float* __restrict__ bk,
    const float* __restrict__ Wv, const float* __restrict__ bv,
    float* __restrict__ qT, float* __restrict__ ko, float* __restrict__ vo)
{
    const int tid  = threadIdx.x;
    const int lane = tid & 63;
    const int p    = blockIdx.x * 64 + lane;
    const int o0   = __builtin_amdgcn_readfirstlane((tid >> 6) * 16);
    const int z    = blockIdx.y;
    const float* Wm = (z == 0) ? Wq : (z == 1) ? Wk : Wv;
    const float* bm = (z == 0) ? bq : (z == 1) ? bk : bv;

    float xr[C];
#pragma unroll
    for (int c = 0; c < C; ++c) xr[c] = x[c * NPIX + p];

    float acc[16];
#pragma unroll
    for (int j = 0; j < 16; ++j) acc[j] = bm[o0 + j];

#pragma unroll 8
    for (int c = 0; c < C; ++c) {
        const float xv = xr[c];
#pragma unroll
        for (int j = 0; j < 16; ++j)
            acc[j] += Wm[(o0 + j) * C + c] * xv;
    }

    if (z == 0) {
#pragma unroll
        for (int j = 0; j < 16; j += 4)
            *(float4*)(qT + (size_t)p * C + o0 + j) =
                make_float4(acc[j], acc[j + 1], acc[j + 2], acc[j + 3]);
    } else {
        float* outm = (z == 1) ? ko : vo;
#pragma unroll
        for (int j = 0; j < 16; ++j)
            outm[(o0 + j) * NPIX + p] = acc[j];
    }
}

// ---------------------------------------------------------------------------
// 2) fused row-Gram + diagonal 7-sum:
//    S[w',kk] = sum_c q[c,h,w'] * k[c,h,kk]   for w' in [w0-3, w0+18]
//    Sd[h,w,kk] = sum_dd S[w+dd, kk+dd]       for w in [w0, w0+15]
//    S tile lives only in LDS (22x130, conflict-free); halo recompute 22/16.
//    k column in VGPRs; q rows wave-uniform -> s_load.
//    grid (H, 8) = 1024 blocks, block 256
// ---------------------------------------------------------------------------
__global__ __launch_bounds__(256) void k_gramd(
    const float* __restrict__ qT, const float* __restrict__ kmat,
    float* __restrict__ Sd)
{
    __shared__ float Sl[22][130];    // 11.4 KB
    const int h   = blockIdx.x;
    const int w0  = blockIdx.y * 16;
    const int tid = threadIdx.x;
    const int kk  = tid & 127;
    const int wsl = tid >> 7;        // 0/1, wave-uniform

    float ksr[C];
#pragma unroll
    for (int c = 0; c < C; ++c) ksr[c] = kmat[c * NPIX + h * W + kk];

    for (int j = 0; j < 11; ++j) {
        int row = wsl * 11 + j;              // 0..21, wave-uniform
        int wp  = w0 - 3 + row;
        float val = 0.f;
        if (wp >= 0 && wp < W) {             // wave-uniform branch
            int wu = __builtin_amdgcn_readfirstlane(wp);
            const float* qrow = qT + (size_t)(h * W + wu) * C;  // SGPR base
            float a0 = 0.f, a1 = 0.f, a2 = 0.f, a3 = 0.f;
#pragma unroll
            for (int c = 0; c < C; c += 4) {
                a0 += qrow[c + 0] * ksr[c + 0];
                a1 += qrow[c + 1] * ksr[c + 1];
                a2 += qrow[c + 2] * ksr[c + 2];
                a3 += qrow[c + 3] * ksr[c + 3];
            }
            val = (a0 + a1) + (a2 + a3);
        }
        Sl[row][kk] = val;
    }
    __syncthreads();

#pragma unroll
    for (int r = 0; r < 8; ++r) {
        int wl = wsl * 8 + r;                // 0..15
        float a = 0.f;
#pragma unroll
        for (int dd = -PAD; dd <= PAD; ++dd) {
            int kj = kk + dd;
            if (kj >= 0 && kj < W)
                a += Sl[wl + 3 + dd][kj];
        }
        Sd[(size_t)(h * W + w0 + wl) * W + kk] = a;
    }
}

// ---------------------------------------------------------------------------
// 3) fused 7x7 box sum of v. grid (C, H/16), block 256
// ---------------------------------------------------------------------------
__global__ __launch_bounds__(256) void k_box(
    const float* __restrict__ v, float* __restrict__ Vs)
{
    __shared__ float vt[22][128];    // rows h0-3 .. h0+18, zero-padded
    __shared__ float vh[22][128];    // horizontal 7-sums
    const int c   = blockIdx.x;
    const int h0  = blockIdx.y * 16;
    const int tid = threadIdx.x;

    for (int i = tid; i < 22 * 128; i += 256) {
        int r = i >> 7, w = i & 127;
        int h = h0 - 3 + r;
        vt[r][w] = (h >= 0 && h < H) ? v[c * NPIX + h * W + w] : 0.f;
    }
    __syncthreads();
    for (int i = tid; i < 22 * 128; i += 256) {
        int r = i >> 7, w = i & 127;
        float s = 0.f;
#pragma unroll
        for (int d = -PAD; d <= PAD; ++d) {
            int wj = w + d;
            if (wj >= 0 && wj < W) s += vt[r][wj];
        }
        vh[r][w] = s;
    }
    __syncthreads();
    for (int i = tid; i < 16 * 128; i += 256) {
        int r = i >> 7, w = i & 127;
        float s = 0.f;
#pragma unroll
        for (int d = 0; d < 7; ++d) s += vh[r + d][w];
        Vs[c * NPIX + (h0 + r) * W + w] = s;
    }
}

// ---------------------------------------------------------------------------
// 4) vertical 7-sum of Sd + softmax over kk. grid (W, H), block 64 (one wave).
// ---------------------------------------------------------------------------
__global__ __launch_bounds__(64) void k_softmax(
    const float* __restrict__ Sd, float* __restrict__ attn)
{
    const int w    = blockIdx.x;
    const int h    = blockIdx.y;
    const int lane = threadIdx.x;
    const int rowb = w * W;

    float L0 = 0.f, L1 = 0.f;
#pragma unroll
    for (int d = -PAD; d <= PAD; ++d) {
        int hj = h + d;
        if (hj >= 0 && hj < H) {
            const float* p = Sd + (size_t)hj * NPIX + rowb;
            L0 += p[lane];
            L1 += p[lane + 64];
        }
    }
    float m = fmaxf(L0, L1);
#pragma unroll
    for (int off = 32; off > 0; off >>= 1) m = fmaxf(m, __shfl_xor(m, off));
    float e0 = __expf(L0 - m), e1 = __expf(L1 - m);
    float s = e0 + e1;
#pragma unroll
    for (int off = 32; off > 0; off >>= 1) s += __shfl_xor(s, off);
    float inv = 1.f / s;
    attn[(size_t)h * NPIX + rowb + lane]      = e0 * inv;
    attn[(size_t)h * NPIX + rowb + lane + 64] = e1 * inv;
}

// ---------------------------------------------------------------------------
// 5) out[c,h,w] = sum_kk attn[h,w,kk] * Vs[c,h,kk]  — lanes = w, channels
//    wave-uniform -> Vs via s_load; attn LDS-staged (padded). 8 acc chains.
//    grid (H, 4) = 512 blocks, block 256
// ---------------------------------------------------------------------------
__global__ __launch_bounds__(256) void k_out(
    const float* __restrict__ attn, const float* __restrict__ Vs,
    float* __restrict__ out)
{
    __shared__ float As[W][65];      // [w][kk-chunk of 64], 33.3 KB
    const int h   = blockIdx.x;
    const int tid = threadIdx.x;
    const int w   = tid & 127;
    const int c0  = __builtin_amdgcn_readfirstlane(
                        blockIdx.y * 16 + (tid >> 7) * 8);
    const int hb  = h * W;

    float acc[8];
#pragma unroll
    for (int j = 0; j < 8; ++j) acc[j] = 0.f;

    for (int kc = 0; kc < W; kc += 64) {
        __syncthreads();
        for (int i = tid; i < W * 64; i += 256) {
            int kk = i & 63, ww = i >> 6;
            As[ww][kk] = attn[(size_t)h * NPIX + ww * W + kc + kk];
        }
        __syncthreads();
#pragma unroll 4
        for (int kk = 0; kk < 64; ++kk) {
            float a = As[w][kk];
#pragma unroll
            for (int j = 0; j < 8; ++j)
                acc[j] += Vs[(size_t)(c0 + j) * NPIX + hb + kc + kk] * a;
        }
    }

#pragma unroll
    for (int j = 0; j < 8; ++j)
        out[(size_t)(c0 + j) * NPIX + hb + w] = acc[j];
}

// ---------------------------------------------------------------------------
// Workspace: 8M floats = 32 MB used (ws is 268 MB), non-overlapping:
//   qT [0,1M)  k [1M,2M)  v [2M,3M)  Sd [3M,5M)  Vs [5M,6M)  attn [6M,8M)
// ---------------------------------------------------------------------------
extern "C" void kernel_launch(void* const* d_in, const int* in_sizes, int n_in,
                              void* d_out, int out_size, void* d_ws, size_t ws_size,
                              hipStream_t stream)
{
    const float* x  = (const float*)d_in[0];
    const float* Wq = (const float*)d_in[1];
    const float* bq = (const float*)d_in[2];
    const float* Wk = (const float*)d_in[3];
    const float* bk = (const float*)d_in[4];
    const float* Wv = (const float*)d_in[5];
    const float* bv = (const float*)d_in[6];
    float* out = (float*)d_out;

    float* ws = (float*)d_ws;
    const size_t NQ = (size_t)C * NPIX;       // 1M floats
    const size_t NS = (size_t)H * W * W;      // 2M floats

    float* qT   = ws;
    float* k    = ws + NQ;
    float* v    = ws + 2 * NQ;
    float* Sd   = ws + 3 * NQ;
    float* Vsum = ws + 3 * NQ + NS;
    float* attn = ws + 4 * NQ + NS;

    k_conv<<<dim3(NPIX / 64, 3), 256, 0, stream>>>(x, Wq, bq, Wk, bk, Wv, bv, qT, k, v);
    k_gramd<<<dim3(H, 8), 256, 0, stream>>>(qT, k, Sd);
    k_box<<<dim3(C, H / 16), 256, 0, stream>>>(v, Vsum);
    k_softmax<<<dim3(W, H), 64, 0, stream>>>(Sd, attn);
    k_out<<<dim3(H, 4), 256, 0, stream>>>(attn, Vsum, out);
}

// Round 8
// 147.946 us; speedup vs baseline: 1.2049x; 1.0433x over previous
//
#include <hip/hip_runtime.h>

static constexpr int C    = 64;
static constexpr int H    = 128;
static constexpr int W    = 128;
static constexpr int NPIX = H * W;      // 16384
static constexpr int PAD  = 3;          // WS=7 -> +-3

// ---------------------------------------------------------------------------
// 1) conv1x1. Each wave: 64 pixels x 16 output channels; W/b wave-uniform ->
//    scalar loads feeding v_fmac v,s,v; 16 independent acc chains.
//    grid (NPIX/64, 3) = 768 blocks, block 256
// ---------------------------------------------------------------------------
__global__ __launch_bounds__(256) void k_conv(
    const float* __restrict__ x,
    const float* __restrict__ Wq, const float* __restrict__ bq,
    const float* __restrict__ Wk, const float* __restrict__ bk,
    const float* __restrict__ Wv, const float* __restrict__ bv,
    float* __restrict__ qT, float* __restrict__ ko, float* __restrict__ vo)
{
    const int tid  = threadIdx.x;
    const int lane = tid & 63;
    const int p    = blockIdx.x * 64 + lane;
    const int o0   = __builtin_amdgcn_readfirstlane((tid >> 6) * 16);
    const int z    = blockIdx.y;
    const float* Wm = (z == 0) ? Wq : (z == 1) ? Wk : Wv;
    const float* bm = (z == 0) ? bq : (z == 1) ? bk : bv;

    float xr[C];
#pragma unroll
    for (int c = 0; c < C; ++c) xr[c] = x[c * NPIX + p];

    float acc[16];
#pragma unroll
    for (int j = 0; j < 16; ++j) acc[j] = bm[o0 + j];

#pragma unroll 8
    for (int c = 0; c < C; ++c) {
        const float xv = xr[c];
#pragma unroll
        for (int j = 0; j < 16; ++j)
            acc[j] += Wm[(o0 + j) * C + c] * xv;
    }

    if (z == 0) {
#pragma unroll
        for (int j = 0; j < 16; j += 4)
            *(float4*)(qT + (size_t)p * C + o0 + j) =
                make_float4(acc[j], acc[j + 1], acc[j + 2], acc[j + 3]);
    } else {
        float* outm = (z == 1) ? ko : vo;
#pragma unroll
        for (int j = 0; j < 16; ++j)
            outm[(o0 + j) * NPIX + p] = acc[j];
    }
}

// ---------------------------------------------------------------------------
// 2) merged dispatch: [gram+diag] (blocks 0..1023) and [7x7 box of v]
//    (blocks 1024..2047). Independent dependency chains -> co-scheduled.
//    LDS: union, 22.5 KB max. block 256.
// ---------------------------------------------------------------------------
__global__ __launch_bounds__(256) void k_mid(
    const float* __restrict__ qT, const float* __restrict__ kmat,
    const float* __restrict__ v,
    float* __restrict__ Sd, float* __restrict__ Vs)
{
    __shared__ union {
        float Sl[22][130];           // gram+diag tile, 11.4 KB
        struct { float vt[22][128]; float vh[22][128]; } box;  // 22.5 KB
    } u;
    const int bid = blockIdx.x;
    const int tid = threadIdx.x;

    if (bid < 1024) {
        // ----- fused row-Gram + diagonal 7-sum -----
        // S[w',kk] = sum_c q[c,h,w']*k[c,h,kk] for w' in [w0-3, w0+18]
        // Sd[h,w,kk] = sum_dd S[w+dd, kk+dd]
        const int h   = bid >> 3;
        const int w0  = (bid & 7) * 16;
        const int kk  = tid & 127;
        const int wsl = tid >> 7;            // 0/1, wave-uniform

        float ksr[C];
#pragma unroll
        for (int c = 0; c < C; ++c) ksr[c] = kmat[c * NPIX + h * W + kk];

        for (int j = 0; j < 11; ++j) {
            int row = wsl * 11 + j;          // 0..21, wave-uniform
            int wp  = w0 - 3 + row;
            float val = 0.f;
            if (wp >= 0 && wp < W) {         // wave-uniform branch
                int wu = __builtin_amdgcn_readfirstlane(wp);
                const float* qrow = qT + (size_t)(h * W + wu) * C;  // SGPR base
                float a0 = 0.f, a1 = 0.f, a2 = 0.f, a3 = 0.f;
#pragma unroll
                for (int c = 0; c < C; c += 4) {
                    a0 += qrow[c + 0] * ksr[c + 0];
                    a1 += qrow[c + 1] * ksr[c + 1];
                    a2 += qrow[c + 2] * ksr[c + 2];
                    a3 += qrow[c + 3] * ksr[c + 3];
                }
                val = (a0 + a1) + (a2 + a3);
            }
            u.Sl[row][kk] = val;
        }
        __syncthreads();

#pragma unroll
        for (int r = 0; r < 8; ++r) {
            int wl = wsl * 8 + r;            // 0..15
            float a = 0.f;
#pragma unroll
            for (int dd = -PAD; dd <= PAD; ++dd) {
                int kj = kk + dd;
                if (kj >= 0 && kj < W)
                    a += u.Sl[wl + 3 + dd][kj];
            }
            Sd[(size_t)(h * W + w0 + wl) * W + kk] = a;
        }
    } else {
        // ----- 7x7 box sum of v (separable in LDS) -----
        const int b2 = bid - 1024;
        const int c  = b2 >> 3;              // 0..127? no: C=64 channels!
        // NOTE: C=64, H/16=8 -> 512 box blocks needed; blocks 1536..2047 idle-
        // guard below. (kept grid at 2048 for symmetric halves)
        if (c >= C) return;
        const int h0 = (b2 & 7) * 16;

        for (int i = tid; i < 22 * 128; i += 256) {
            int r = i >> 7, w = i & 127;
            int h = h0 - 3 + r;
            u.box.vt[r][w] = (h >= 0 && h < H) ? v[c * NPIX + h * W + w] : 0.f;
        }
        __syncthreads();
        for (int i = tid; i < 22 * 128; i += 256) {
            int r = i >> 7, w = i & 127;
            float s = 0.f;
#pragma unroll
            for (int d = -PAD; d <= PAD; ++d) {
                int wj = w + d;
                if (wj >= 0 && wj < W) s += u.box.vt[r][wj];
            }
            u.box.vh[r][w] = s;
        }
        __syncthreads();
        for (int i = tid; i < 16 * 128; i += 256) {
            int r = i >> 7, w = i & 127;
            float s = 0.f;
#pragma unroll
            for (int d = 0; d < 7; ++d) s += u.box.vh[r + d][w];
            Vs[c * NPIX + (h0 + r) * W + w] = s;
        }
    }
}

// ---------------------------------------------------------------------------
// 3) vertical 7-sum of Sd + softmax over kk. 4 waves/block, 1 pixel per wave.
//    grid 4096, block 256.
// ---------------------------------------------------------------------------
__global__ __launch_bounds__(256) void k_softmax(
    const float* __restrict__ Sd, float* __restrict__ attn)
{
    const int pix  = blockIdx.x * 4 + (threadIdx.x >> 6);   // w*H-ish flat
    const int w    = pix >> 7;
    const int h    = pix & 127;
    const int lane = threadIdx.x & 63;
    const int rowb = w * W;

    float L0 = 0.f, L1 = 0.f;
#pragma unroll
    for (int d = -PAD; d <= PAD; ++d) {
        int hj = h + d;
        if (hj >= 0 && hj < H) {
            const float* p = Sd + (size_t)hj * NPIX + rowb;
            L0 += p[lane];
            L1 += p[lane + 64];
        }
    }
    float m = fmaxf(L0, L1);
#pragma unroll
    for (int off = 32; off > 0; off >>= 1) m = fmaxf(m, __shfl_xor(m, off));
    float e0 = __expf(L0 - m), e1 = __expf(L1 - m);
    float s = e0 + e1;
#pragma unroll
    for (int off = 32; off > 0; off >>= 1) s += __shfl_xor(s, off);
    float inv = 1.f / s;
    attn[(size_t)h * NPIX + rowb + lane]      = e0 * inv;
    attn[(size_t)h * NPIX + rowb + lane + 64] = e1 * inv;
}

// ---------------------------------------------------------------------------
// 4) out[c,h,w] = sum_kk attn[h,w,kk] * Vs[c,h,kk]  — lanes = w, channels
//    wave-uniform -> Vs via s_load; attn LDS-staged (padded). 8 acc chains.
//    grid (H, 4) = 512 blocks, block 256
// ---------------------------------------------------------------------------
__global__ __launch_bounds__(256) void k_out(
    const float* __restrict__ attn, const float* __restrict__ Vs,
    float* __restrict__ out)
{
    __shared__ float As[W][65];      // [w][kk-chunk of 64], 33.3 KB
    const int h   = blockIdx.x;
    const int tid = threadIdx.x;
    const int w   = tid & 127;
    const int c0  = __builtin_amdgcn_readfirstlane(
                        blockIdx.y * 16 + (tid >> 7) * 8);
    const int hb  = h * W;

    float acc[8];
#pragma unroll
    for (int j = 0; j < 8; ++j) acc[j] = 0.f;

    for (int kc = 0; kc < W; kc += 64) {
        __syncthreads();
        for (int i = tid; i < W * 64; i += 256) {
            int kk = i & 63, ww = i >> 6;
            As[ww][kk] = attn[(size_t)h * NPIX + ww * W + kc + kk];
        }
        __syncthreads();
#pragma unroll 4
        for (int kk = 0; kk < 64; ++kk) {
            float a = As[w][kk];
#pragma unroll
            for (int j = 0; j < 8; ++j)
                acc[j] += Vs[(size_t)(c0 + j) * NPIX + hb + kc + kk] * a;
        }
    }

#pragma unroll
    for (int j = 0; j < 8; ++j)
        out[(size_t)(c0 + j) * NPIX + hb + w] = acc[j];
}

// ---------------------------------------------------------------------------
// Workspace: 8M floats = 32 MB used (ws is 268 MB), non-overlapping:
//   qT [0,1M)  k [1M,2M)  v [2M,3M)  Sd [3M,5M)  Vs [5M,6M)  attn [6M,8M)
// ---------------------------------------------------------------------------
extern "C" void kernel_launch(void* const* d_in, const int* in_sizes, int n_in,
                              void* d_out, int out_size, void* d_ws, size_t ws_size,
                              hipStream_t stream)
{
    const float* x  = (const float*)d_in[0];
    const float* Wq = (const float*)d_in[1];
    const float* bq = (const float*)d_in[2];
    const float* Wk = (const float*)d_in[3];
    const float* bk = (const float*)d_in[4];
    const float* Wv = (const float*)d_in[5];
    const float* bv = (const float*)d_in[6];
    float* out = (float*)d_out;

    float* ws = (float*)d_ws;
    const size_t NQ = (size_t)C * NPIX;       // 1M floats
    const size_t NS = (size_t)H * W * W;      // 2M floats

    float* qT   = ws;
    float* k    = ws + NQ;
    float* v    = ws + 2 * NQ;
    float* Sd   = ws + 3 * NQ;
    float* Vsum = ws + 3 * NQ + NS;
    float* attn = ws + 4 * NQ + NS;

    k_conv<<<dim3(NPIX / 64, 3), 256, 0, stream>>>(x, Wq, bq, Wk, bk, Wv, bv, qT, k, v);
    k_mid<<<dim3(2048), 256, 0, stream>>>(qT, k, v, Sd, Vsum);
    k_softmax<<<dim3(NPIX / 4), 256, 0, stream>>>(Sd, attn);
    k_out<<<dim3(H, 4), 256, 0, stream>>>(attn, Vsum, out);
}

// Round 9
// 144.340 us; speedup vs baseline: 1.2350x; 1.0250x over previous
//
#include <hip/hip_runtime.h>

static constexpr int C    = 64;
static constexpr int H    = 128;
static constexpr int W    = 128;
static constexpr int NPIX = H * W;      // 16384
static constexpr int PAD  = 3;          // WS=7 -> +-3

// ---------------------------------------------------------------------------
// 1) conv1x1. Each wave: 64 pixels x 16 output channels; W/b wave-uniform ->
//    scalar loads feeding v_fmac v,s,v; 16 independent acc chains.
//    grid (NPIX/64, 3) = 768 blocks, block 256
// ---------------------------------------------------------------------------
__global__ __launch_bounds__(256) void k_conv(
    const float* __restrict__ x,
    const float* __restrict__ Wq, const float* __restrict__ bq,
    const float* __restrict__ Wk, const float* __restrict__ bk,
    const float* __restrict__ Wv, const float* __restrict__ bv,
    float* __restrict__ qT, float* __restrict__ ko, float* __restrict__ vo)
{
    const int tid  = threadIdx.x;
    const int lane = tid & 63;
    const int p    = blockIdx.x * 64 + lane;
    const int o0   = __builtin_amdgcn_readfirstlane((tid >> 6) * 16);
    const int z    = blockIdx.y;
    const float* Wm = (z == 0) ? Wq : (z == 1) ? Wk : Wv;
    const float* bm = (z == 0) ? bq : (z == 1) ? bk : bv;

    float xr[C];
#pragma unroll
    for (int c = 0; c < C; ++c) xr[c] = x[c * NPIX + p];

    float acc[16];
#pragma unroll
    for (int j = 0; j < 16; ++j) acc[j] = bm[o0 + j];

#pragma unroll 8
    for (int c = 0; c < C; ++c) {
        const float xv = xr[c];
#pragma unroll
        for (int j = 0; j < 16; ++j)
            acc[j] += Wm[(o0 + j) * C + c] * xv;
    }

    if (z == 0) {
#pragma unroll
        for (int j = 0; j < 16; j += 4)
            *(float4*)(qT + (size_t)p * C + o0 + j) =
                make_float4(acc[j], acc[j + 1], acc[j + 2], acc[j + 3]);
    } else {
        float* outm = (z == 1) ? ko : vo;
#pragma unroll
        for (int j = 0; j < 16; ++j)
            outm[(o0 + j) * NPIX + p] = acc[j];
    }
}

// ---------------------------------------------------------------------------
// 2) merged dispatch: [gram+diag] (blocks 0..1023) and [7x7 box of v]
//    (blocks 1024..1535). Independent chains -> co-scheduled. block 256.
// ---------------------------------------------------------------------------
__global__ __launch_bounds__(256) void k_mid(
    const float* __restrict__ qT, const float* __restrict__ kmat,
    const float* __restrict__ v,
    float* __restrict__ Sd, float* __restrict__ Vs)
{
    __shared__ union {
        float Sl[22][130];           // gram+diag tile, 11.4 KB
        struct { float vt[22][128]; float vh[22][128]; } box;  // 22.5 KB
    } u;
    const int bid = blockIdx.x;
    const int tid = threadIdx.x;

    if (bid < 1024) {
        // ----- fused row-Gram + diagonal 7-sum -----
        const int h   = bid >> 3;
        const int w0  = (bid & 7) * 16;
        const int kk  = tid & 127;
        const int wsl = tid >> 7;            // 0/1, wave-uniform

        float ksr[C];
#pragma unroll
        for (int c = 0; c < C; ++c) ksr[c] = kmat[c * NPIX + h * W + kk];

        for (int j = 0; j < 11; ++j) {
            int row = wsl * 11 + j;          // 0..21, wave-uniform
            int wp  = w0 - 3 + row;
            float val = 0.f;
            if (wp >= 0 && wp < W) {         // wave-uniform branch
                int wu = __builtin_amdgcn_readfirstlane(wp);
                const float* qrow = qT + (size_t)(h * W + wu) * C;  // SGPR base
                float a0 = 0.f, a1 = 0.f, a2 = 0.f, a3 = 0.f;
#pragma unroll
                for (int c = 0; c < C; c += 4) {
                    a0 += qrow[c + 0] * ksr[c + 0];
                    a1 += qrow[c + 1] * ksr[c + 1];
                    a2 += qrow[c + 2] * ksr[c + 2];
                    a3 += qrow[c + 3] * ksr[c + 3];
                }
                val = (a0 + a1) + (a2 + a3);
            }
            u.Sl[row][kk] = val;
        }
        __syncthreads();

#pragma unroll
        for (int r = 0; r < 8; ++r) {
            int wl = wsl * 8 + r;            // 0..15
            float a = 0.f;
#pragma unroll
            for (int dd = -PAD; dd <= PAD; ++dd) {
                int kj = kk + dd;
                if (kj >= 0 && kj < W)
                    a += u.Sl[wl + 3 + dd][kj];
            }
            Sd[(size_t)(h * W + w0 + wl) * W + kk] = a;
        }
    } else {
        // ----- 7x7 box sum of v (separable in LDS) -----
        const int b2 = bid - 1024;           // 0..511
        const int c  = b2 >> 3;              // 0..63
        const int h0 = (b2 & 7) * 16;

        for (int i = tid; i < 22 * 128; i += 256) {
            int r = i >> 7, w = i & 127;
            int h = h0 - 3 + r;
            u.box.vt[r][w] = (h >= 0 && h < H) ? v[c * NPIX + h * W + w] : 0.f;
        }
        __syncthreads();
        for (int i = tid; i < 22 * 128; i += 256) {
            int r = i >> 7, w = i & 127;
            float s = 0.f;
#pragma unroll
            for (int d = -PAD; d <= PAD; ++d) {
                int wj = w + d;
                if (wj >= 0 && wj < W) s += u.box.vt[r][wj];
            }
            u.box.vh[r][w] = s;
        }
        __syncthreads();
        for (int i = tid; i < 16 * 128; i += 256) {
            int r = i >> 7, w = i & 127;
            float s = 0.f;
#pragma unroll
            for (int d = 0; d < 7; ++d) s += u.box.vh[r + d][w];
            Vs[c * NPIX + (h0 + r) * W + w] = s;
        }
    }
}

// ---------------------------------------------------------------------------
// 3) vertical 7-sum of Sd + softmax, h-tiled: block = (w, 16-h tile).
//    Sd rows h0-3..h0+18 staged in LDS (22x132 pad -> conflict-free), then
//    16 lanes per h (8 kk each, stride 16), 16-lane shuffle softmax.
//    Reads 22/16 x 8 MB = 11 MB (was 7x = 56 MB). grid (W, H/16), block 256.
// ---------------------------------------------------------------------------
__global__ __launch_bounds__(256) void k_softmax(
    const float* __restrict__ Sd, float* __restrict__ attn)
{
    __shared__ float Sl[22][132];    // 11.6 KB
    const int w   = blockIdx.x;
    const int h0  = blockIdx.y * 16;
    const int tid = threadIdx.x;

    for (int i = tid; i < 22 * 128; i += 256) {
        int r = i >> 7, kk = i & 127;
        int h = h0 - 3 + r;
        Sl[r][kk] = (h >= 0 && h < H)
                  ? Sd[(size_t)h * NPIX + w * W + kk] : 0.f;
    }
    __syncthreads();

    const int hl  = tid >> 4;        // 0..15 (h within tile)
    const int sub = tid & 15;        // kk % 16

    float lg[8];
#pragma unroll
    for (int r = 0; r < 8; ++r) {
        int kk = sub + 16 * r;
        float a = 0.f;
#pragma unroll
        for (int d = 0; d < 7; ++d) a += Sl[hl + d][kk];
        lg[r] = a;
    }

    float m = lg[0];
#pragma unroll
    for (int r = 1; r < 8; ++r) m = fmaxf(m, lg[r]);
#pragma unroll
    for (int off = 1; off <= 8; off <<= 1) m = fmaxf(m, __shfl_xor(m, off));
    float ssum = 0.f;
#pragma unroll
    for (int r = 0; r < 8; ++r) { lg[r] = __expf(lg[r] - m); ssum += lg[r]; }
#pragma unroll
    for (int off = 1; off <= 8; off <<= 1) ssum += __shfl_xor(ssum, off);
    float inv = 1.f / ssum;

    float* arow = attn + (size_t)(h0 + hl) * NPIX + (size_t)w * W;
#pragma unroll
    for (int r = 0; r < 8; ++r) arow[sub + 16 * r] = lg[r] * inv;
}

// ---------------------------------------------------------------------------
// 4) out[c,h,w] = sum_kk attn[h,w,kk] * Vs[c,h,kk]  — lanes = w, channels
//    wave-uniform -> Vs via s_load; attn LDS-staged (padded). 8 acc chains.
//    grid (H, 4) = 512 blocks, block 256
// ---------------------------------------------------------------------------
__global__ __launch_bounds__(256) void k_out(
    const float* __restrict__ attn, const float* __restrict__ Vs,
    float* __restrict__ out)
{
    __shared__ float As[W][65];      // [w][kk-chunk of 64], 33.3 KB
    const int h   = blockIdx.x;
    const int tid = threadIdx.x;
    const int w   = tid & 127;
    const int c0  = __builtin_amdgcn_readfirstlane(
                        blockIdx.y * 16 + (tid >> 7) * 8);
    const int hb  = h * W;

    float acc[8];
#pragma unroll
    for (int j = 0; j < 8; ++j) acc[j] = 0.f;

    for (int kc = 0; kc < W; kc += 64) {
        __syncthreads();
        for (int i = tid; i < W * 64; i += 256) {
            int kk = i & 63, ww = i >> 6;
            As[ww][kk] = attn[(size_t)h * NPIX + ww * W + kc + kk];
        }
        __syncthreads();
#pragma unroll 4
        for (int kk = 0; kk < 64; ++kk) {
            float a = As[w][kk];
#pragma unroll
            for (int j = 0; j < 8; ++j)
                acc[j] += Vs[(size_t)(c0 + j) * NPIX + hb + kc + kk] * a;
        }
    }

#pragma unroll
    for (int j = 0; j < 8; ++j)
        out[(size_t)(c0 + j) * NPIX + hb + w] = acc[j];
}

// ---------------------------------------------------------------------------
// Workspace: 8M floats = 32 MB used (ws is 268 MB), non-overlapping:
//   qT [0,1M)  k [1M,2M)  v [2M,3M)  Sd [3M,5M)  Vs [5M,6M)  attn [6M,8M)
// ---------------------------------------------------------------------------
extern "C" void kernel_launch(void* const* d_in, const int* in_sizes, int n_in,
                              void* d_out, int out_size, void* d_ws, size_t ws_size,
                              hipStream_t stream)
{
    const float* x  = (const float*)d_in[0];
    const float* Wq = (const float*)d_in[1];
    const float* bq = (const float*)d_in[2];
    const float* Wk = (const float*)d_in[3];
    const float* bk = (const float*)d_in[4];
    const float* Wv = (const float*)d_in[5];
    const float* bv = (const float*)d_in[6];
    float* out = (float*)d_out;

    float* ws = (float*)d_ws;
    const size_t NQ = (size_t)C * NPIX;       // 1M floats
    const size_t NS = (size_t)H * W * W;      // 2M floats

    float* qT   = ws;
    float* k    = ws + NQ;
    float* v    = ws + 2 * NQ;
    float* Sd   = ws + 3 * NQ;
    float* Vsum = ws + 3 * NQ + NS;
    float* attn = ws + 4 * NQ + NS;

    k_conv<<<dim3(NPIX / 64, 3), 256, 0, stream>>>(x, Wq, bq, Wk, bk, Wv, bv, qT, k, v);
    k_mid<<<dim3(1536), 256, 0, stream>>>(qT, k, v, Sd, Vsum);
    k_softmax<<<dim3(W, H / 16), 256, 0, stream>>>(Sd, attn);
    k_out<<<dim3(H, 4), 256, 0, stream>>>(attn, Vsum, out);
}